// Round 4
// baseline (169.605 us; speedup 1.0000x reference)
//
#include <hip/hip_runtime.h>

#define B_  512
#define S_  200
#define M_  102400

typedef short bf16x8 __attribute__((ext_vector_type(8)));
typedef float f32x4  __attribute__((ext_vector_type(4)));
typedef unsigned short u16;
typedef u16 us4 __attribute__((ext_vector_type(4)));
typedef unsigned int u32;

#define MFMA16 __builtin_amdgcn_mfma_f32_16x16x32_bf16
#define GLDS(gp, lp) __builtin_amdgcn_global_load_lds( \
    (const __attribute__((address_space(1))) unsigned int*)(gp), \
    (__attribute__((address_space(3))) unsigned int*)(lp), 16, 0, 0)

__device__ __forceinline__ u16 f2bf(float f) {
    union { float f; unsigned u; } v; v.f = f;
    unsigned r = v.u + 0x7fffu + ((v.u >> 16) & 1u);
    return (u16)(r >> 16);
}
__device__ __forceinline__ float bf2f(u16 x) {
    union { unsigned u; float f; } v; v.u = ((unsigned)x) << 16;
    return v.f;
}
__device__ __forceinline__ int swz(int row, int b) { return b ^ ((row & 7) << 4); }

// ws layout (u16 units)
#define WQ_OFF   0
#define WK_OFF   16384
#define WV_OFF   32768
#define W1_OFF   49152
#define W2_OFF   114688
#define BQS_OFF  180224
#define QB_OFF   262144   // also Xb (aliased)
#define KB_OFF   (QB_OFF + 13107200)
#define VB_OFF   (KB_OFF + 13107200)

// ---------------------------------------------------------------------------
__global__ __launch_bounds__(256) void cvt_kernel(
    const float* __restrict__ Wq, const float* __restrict__ bq,
    const float* __restrict__ Wk, const float* __restrict__ Wv,
    const float* __restrict__ W1, const float* __restrict__ W2,
    u16* __restrict__ wdst, float* __restrict__ bqs)
{
    const float QSC = 0.17677669529663689f;
    int idx = blockIdx.x * 256 + threadIdx.x;
    if (idx < 128) bqs[idx] = bq[idx] * QSC;
    if (idx < 49152) {
        int wsel = idx >> 14, r = (idx >> 7) & 127, c = idx & 127;
        const float* src = wsel == 0 ? Wq : (wsel == 1 ? Wk : Wv);
        float v = src[idx & 16383];
        if (wsel == 0) v *= QSC;
        *(u16*)((char*)(wdst + wsel * 16384) + r * 256 + swz(r, 2 * c)) = f2bf(v);
    } else if (idx < 114688) {
        int i = idx - 49152;
        int r_g = i >> 7, c = i & 127;
        int sub = r_g >> 6, fr = r_g & 63;
        *(u16*)((char*)(wdst + W1_OFF) + sub * 16384 + fr * 256 + ((2 * c) ^ ((fr & 7) << 4)))
            = f2bf(W1[i]);
    } else if (idx < 180224) {
        int i = idx - 114688;
        int r_out = i >> 9, c_ff = i & 511;
        int sub = c_ff >> 6, lc = c_ff & 63;
        *(u16*)((char*)(wdst + W2_OFF) + sub * 16384 + r_out * 128 + ((2 * lc) ^ ((r_out & 7) << 4)))
            = f2bf(W2[i]);
    }
}

// ---------------------------------------------------------------------------
// Q projection -> swizzled bf16 Qb (pre-scaled by 1/sqrt(D))
// ---------------------------------------------------------------------------
__global__ __launch_bounds__(256) void proj_q_kernel(
    const float* __restrict__ X, const u16* __restrict__ Ws,
    const float* __restrict__ bqs, u16* __restrict__ Y)
{
    __shared__ __align__(16) u16 sW[16384];
    const int tid = threadIdx.x, w = tid >> 6, lane = tid & 63;
    const int lo = lane & 15, hi = lane >> 4;
    const int base = blockIdx.x * 128;

#pragma unroll
    for (int k = 0; k < 8; ++k) {
        int seg = w * 8 + k;
        GLDS((const char*)Ws + seg * 1024 + lane * 16, (char*)sW + seg * 1024);
    }

    bf16x8 a[2][4];
#pragma unroll
    for (int t = 0; t < 2; ++t) {
        const float* rp = X + (size_t)(base + w * 32 + t * 16 + lo) * 128;
#pragma unroll
        for (int ks = 0; ks < 4; ++ks) {
            float4 v0 = *(const float4*)(rp + ks * 32 + hi * 8);
            float4 v1 = *(const float4*)(rp + ks * 32 + hi * 8 + 4);
            union { bf16x8 v; u16 s[8]; } af;
            af.s[0]=f2bf(v0.x); af.s[1]=f2bf(v0.y); af.s[2]=f2bf(v0.z); af.s[3]=f2bf(v0.w);
            af.s[4]=f2bf(v1.x); af.s[5]=f2bf(v1.y); af.s[6]=f2bf(v1.z); af.s[7]=f2bf(v1.w);
            a[t][ks] = af.v;
        }
    }
    asm volatile("s_waitcnt vmcnt(0)" ::: "memory");
    __builtin_amdgcn_s_barrier();

#pragma unroll
    for (int n = 0; n < 8; ++n) {
        bf16x8 bf[4];
#pragma unroll
        for (int ks = 0; ks < 4; ++ks)
            bf[ks] = *(const bf16x8*)((const char*)sW + (n*16+lo)*256 + swz(lo, ks*64 + hi*16));
        float bb = bqs[n * 16 + lo];
#pragma unroll
        for (int t = 0; t < 2; ++t) {
            f32x4 acc = {0.f, 0.f, 0.f, 0.f};
#pragma unroll
            for (int ks = 0; ks < 4; ++ks) acc = MFMA16(a[t][ks], bf[ks], acc, 0, 0, 0);
#pragma unroll
            for (int r = 0; r < 4; ++r) {
                int row = base + w * 32 + t * 16 + hi * 4 + r;
                *(u16*)((char*)Y + (size_t)row * 256 + swz(row, n * 32 + 2 * lo)) =
                    f2bf(acc[r] + bb);
            }
        }
    }
}

// ---------------------------------------------------------------------------
// Fused K/V projection. Plain [M][128] bf16 outputs.
// ---------------------------------------------------------------------------
__global__ __launch_bounds__(256) void proj_kv_kernel(
    const float* __restrict__ X, const u16* __restrict__ Wks, const u16* __restrict__ Wvs,
    const float* __restrict__ bk, const float* __restrict__ bv,
    u16* __restrict__ K, u16* __restrict__ V)
{
    __shared__ __align__(16) u16 sWk[16384];
    __shared__ __align__(16) u16 sWv[16384];
    const int tid = threadIdx.x, w = tid >> 6, lane = tid & 63;
    const int lo = lane & 15, hi = lane >> 4;
    const int base = blockIdx.x * 128;

#pragma unroll
    for (int k = 0; k < 8; ++k) {
        int seg = w * 8 + k;
        GLDS((const char*)Wks + seg * 1024 + lane * 16, (char*)sWk + seg * 1024);
        GLDS((const char*)Wvs + seg * 1024 + lane * 16, (char*)sWv + seg * 1024);
    }

    bf16x8 a[2][4];
#pragma unroll
    for (int t = 0; t < 2; ++t) {
        const float* rp = X + (size_t)(base + w * 32 + t * 16 + lo) * 128;
#pragma unroll
        for (int ks = 0; ks < 4; ++ks) {
            float4 v0 = *(const float4*)(rp + ks * 32 + hi * 8);
            float4 v1 = *(const float4*)(rp + ks * 32 + hi * 8 + 4);
            union { bf16x8 v; u16 s[8]; } af;
            af.s[0]=f2bf(v0.x); af.s[1]=f2bf(v0.y); af.s[2]=f2bf(v0.z); af.s[3]=f2bf(v0.w);
            af.s[4]=f2bf(v1.x); af.s[5]=f2bf(v1.y); af.s[6]=f2bf(v1.z); af.s[7]=f2bf(v1.w);
            a[t][ks] = af.v;
        }
    }
    asm volatile("s_waitcnt vmcnt(0)" ::: "memory");
    __builtin_amdgcn_s_barrier();

#pragma unroll
    for (int n = 0; n < 8; ++n) {
        bf16x8 bf[4];
#pragma unroll
        for (int ks = 0; ks < 4; ++ks)
            bf[ks] = *(const bf16x8*)((const char*)sWk + (n*16+lo)*256 + swz(lo, ks*64 + hi*16));
        float bb = bk[n * 16 + lo];
#pragma unroll
        for (int t = 0; t < 2; ++t) {
            f32x4 acc = {0.f, 0.f, 0.f, 0.f};
#pragma unroll
            for (int ks = 0; ks < 4; ++ks) acc = MFMA16(a[t][ks], bf[ks], acc, 0, 0, 0);
#pragma unroll
            for (int r = 0; r < 4; ++r) {
                size_t row = base + w * 32 + t * 16 + hi * 4 + r;
                K[row * 128 + n * 16 + lo] = f2bf(acc[r] + bb);
            }
        }
    }
#pragma unroll
    for (int n = 0; n < 8; ++n) {
        bf16x8 bf[4];
#pragma unroll
        for (int ks = 0; ks < 4; ++ks)
            bf[ks] = *(const bf16x8*)((const char*)sWv + (n*16+lo)*256 + swz(lo, ks*64 + hi*16));
        float bb = bv[n * 16 + lo];
#pragma unroll
        for (int t = 0; t < 2; ++t) {
            f32x4 acc = {0.f, 0.f, 0.f, 0.f};
#pragma unroll
            for (int ks = 0; ks < 4; ++ks) acc = MFMA16(a[t][ks], bf[ks], acc, 0, 0, 0);
#pragma unroll
            for (int r = 0; r < 4; ++r) {
                size_t row = base + w * 32 + t * 16 + hi * 4 + r;
                V[row * 128 + n * 16 + lo] = f2bf(acc[r] + bb);
            }
        }
    }
}

// ---------------------------------------------------------------------------
// Attention: swapped QK^T (S^T in regs), in-register P assembly (no LDS P),
// permuted-k PV. One wg per (b,h); no-max softmax (scores provably tiny).
// k-slot mapping per 32-key chunk: k = 8*hi + 4*blk + r  <->  key = c0 + 16*blk + 4*hi + r
// ---------------------------------------------------------------------------
__global__ __launch_bounds__(256) void attn_kernel(
    const u16* __restrict__ Qb, const u16* __restrict__ Kb, const u16* __restrict__ Vb,
    const int* __restrict__ mask, const float* __restrict__ queries, u16* __restrict__ Xb)
{
    __shared__ __align__(16) u16  sK[224][40];     // key pos x d
    __shared__ __align__(16) u16  sVt[32][248];    // d x permuted key pos
    __shared__ __align__(16) float sBiasP[224];    // permuted mask bias

    const int tid = threadIdx.x;
    const int b   = blockIdx.x >> 2;
    const int h   = blockIdx.x & 3;
    const size_t rowbase = (size_t)b * 200;

    // K: 16B vector loads
    for (int slot = tid; slot < 800; slot += 256) {
        int s = slot >> 2, part = slot & 3;
        *(bf16x8*)&sK[s][part * 8] =
            *(const bf16x8*)(Kb + (rowbase + s) * 128 + h * 32 + part * 8);
    }
    if (tid < 96) {
        int s = 200 + (tid >> 2), part = tid & 3;
        bf16x8 z = {0,0,0,0,0,0,0,0};
        *(bf16x8*)&sK[s][part * 8] = z;
    }
    // V^T, permuted key positions (4-aligned groups stay contiguous)
    for (int slot = tid; slot < 1792; slot += 256) {
        int d = slot & 31, sg = slot >> 5;
        int s0 = sg * 4;
        int c0 = s0 & ~31, a = (s0 & 31) >> 2;
        int pos = c0 + (a & 3) * 8 + (a >> 2) * 4;
        us4 v;
#pragma unroll
        for (int j = 0; j < 4; ++j) {
            int s = s0 + j;
            v[j] = (s < 200) ? Vb[(rowbase + s) * 128 + h * 32 + d] : (u16)0;
        }
        *(us4*)&sVt[d][pos] = v;
    }
    // permuted bias: position p = c0+8h+4blk+r holds bias of key c0+16blk+4h+r
    for (int i = tid; i < 224; i += 256) {
        int c0 = i & ~31, local = i & 31;
        int hh = local >> 3, j = local & 7;
        int blk = j >> 2, r = j & 3;
        int key = c0 + 16 * blk + 4 * hh + r;
        sBiasP[i] = (key < 200 && mask[rowbase + key] != 0) ? 0.f : -1e30f;
    }
    __syncthreads();

    const int w = tid >> 6, lane = tid & 63;
    const int lo = lane & 15, hi = lane >> 4;

    for (int qb = w; qb < 13; qb += 4) {
        int qrow = qb * 16 + lo;
        if (qrow > 199) qrow = 199;
        bf16x8 qf = *(const bf16x8*)((const char*)Qb + (size_t)(rowbase + qrow) * 256
                                      + swz(qrow, h * 64 + hi * 16));

        f32x4 acc0 = {0.f, 0.f, 0.f, 0.f}, acc1 = {0.f, 0.f, 0.f, 0.f};
        float psum = 0.f;

        for (int kt = 0; kt < 7; ++kt) {
            int c0 = kt * 32;
            bf16x8 k0 = *(const bf16x8*)&sK[c0 + lo][hi * 8];
            bf16x8 k1 = *(const bf16x8*)&sK[c0 + 16 + lo][hi * 8];
            f32x4 z = {0.f, 0.f, 0.f, 0.f};
            // swapped: A=K rows, B=Q rows -> lane holds S^T[key=4hi+r][q=lo]
            f32x4 s0 = MFMA16(k0, qf, z, 0, 0, 0);
            f32x4 s1 = MFMA16(k1, qf, z, 0, 0, 0);
            float4 bia0 = *(const float4*)&sBiasP[c0 + hi * 8];
            float4 bia1 = *(const float4*)&sBiasP[c0 + hi * 8 + 4];
            float p00 = __expf(s0[0] + bia0.x);
            float p01 = __expf(s0[1] + bia0.y);
            float p02 = __expf(s0[2] + bia0.z);
            float p03 = __expf(s0[3] + bia0.w);
            float p10 = __expf(s1[0] + bia1.x);
            float p11 = __expf(s1[1] + bia1.y);
            float p12 = __expf(s1[2] + bia1.z);
            float p13 = __expf(s1[3] + bia1.w);
            psum += ((p00 + p01) + (p02 + p03)) + ((p10 + p11) + (p12 + p13));
            // RTZ-pack into PV A-fragment (k-order matches permuted sVt)
            union { bf16x8 v; u32 d[4]; } pa;
            pa.d[0] = (__float_as_uint(p00) >> 16) | (__float_as_uint(p01) & 0xffff0000u);
            pa.d[1] = (__float_as_uint(p02) >> 16) | (__float_as_uint(p03) & 0xffff0000u);
            pa.d[2] = (__float_as_uint(p10) >> 16) | (__float_as_uint(p11) & 0xffff0000u);
            pa.d[3] = (__float_as_uint(p12) >> 16) | (__float_as_uint(p13) & 0xffff0000u);
            bf16x8 v0 = *(const bf16x8*)&sVt[lo][c0 + hi * 8];
            bf16x8 v1 = *(const bf16x8*)&sVt[16 + lo][c0 + hi * 8];
            acc0 = MFMA16(pa.v, v0, acc0, 0, 0, 0);
            acc1 = MFMA16(pa.v, v1, acc1, 0, 0, 0);
        }
        // psum: lane has partial for q=lo over its keys; reduce across hi
        psum += __shfl_xor(psum, 16);
        psum += __shfl_xor(psum, 32);
        float inv = 1.f / psum;          // inv for q=lo, replicated over hi
        float invr[4];
#pragma unroll
        for (int r = 0; r < 4; ++r)
            invr[r] = __shfl(inv, 4 * hi + r, 16);   // inv for q=4hi+r
#pragma unroll
        for (int r = 0; r < 4; ++r) {
            int row = qb * 16 + hi * 4 + r;
            if (row < 200) {
                size_t o  = (rowbase + row) * 128 + h * 32;
                size_t rb = (rowbase + row) * 256;
                *(u16*)((char*)Xb + rb + swz(row, h * 64 + 2 * lo)) =
                    f2bf(acc0[r] * invr[r] + queries[o + lo]);
                *(u16*)((char*)Xb + rb + swz(row, h * 64 + 32 + 2 * lo)) =
                    f2bf(acc1[r] * invr[r] + queries[o + 16 + lo]);
            }
        }
    }
}

// ---------------------------------------------------------------------------
// Fused FFN: out = relu(X@W1^T+b1)@W2^T + b2 + X.  X = swizzled bf16 Xb.
// ---------------------------------------------------------------------------
__global__ __launch_bounds__(256) void ffn_kernel(
    const u16* __restrict__ Xb, const u16* __restrict__ W1s, const u16* __restrict__ W2s,
    const float* __restrict__ b1, const float* __restrict__ b2, float* __restrict__ out)
{
    __shared__ __align__(16) u16 sW1[2][8192];
    __shared__ __align__(16) u16 sW2[2][8192];
    __shared__ __align__(16) u16 sH[4][2048];
    const int tid = threadIdx.x, w = tid >> 6, lane = tid & 63;
    const int lo = lane & 15, hi = lane >> 4;
    const size_t base = (size_t)blockIdx.x * 128;
    const int wrow = w * 32;

#pragma unroll
    for (int k = 0; k < 4; ++k) {
        int seg = w * 4 + k;
        GLDS((const char*)W1s + seg * 1024 + lane * 16, (char*)sW1[0] + seg * 1024);
        GLDS((const char*)W2s + seg * 1024 + lane * 16, (char*)sW2[0] + seg * 1024);
    }

    bf16x8 a[2][4];
#pragma unroll
    for (int t = 0; t < 2; ++t) {
        size_t row = base + wrow + t * 16 + lo;
#pragma unroll
        for (int ks = 0; ks < 4; ++ks)
            a[t][ks] = *(const bf16x8*)((const char*)Xb + row * 256
                                         + ((ks * 64 + hi * 16) ^ ((lo & 7) << 4)));
    }

    f32x4 yacc[2][8];
#pragma unroll
    for (int t = 0; t < 2; ++t)
#pragma unroll
        for (int n = 0; n < 8; ++n) yacc[t][n] = (f32x4){0.f, 0.f, 0.f, 0.f};

    asm volatile("s_waitcnt vmcnt(0)" ::: "memory");
    __builtin_amdgcn_s_barrier();

    for (int sub = 0; sub < 8; ++sub) {
        int cur = sub & 1, nxt = cur ^ 1;
        if (sub < 7) {
#pragma unroll
            for (int k = 0; k < 4; ++k) {
                int seg = w * 4 + k;
                GLDS((const char*)W1s + (sub + 1) * 16384 + seg * 1024 + lane * 16,
                     (char*)sW1[nxt] + seg * 1024);
                GLDS((const char*)W2s + (sub + 1) * 16384 + seg * 1024 + lane * 16,
                     (char*)sW2[nxt] + seg * 1024);
            }
        }
#pragma unroll
        for (int n = 0; n < 4; ++n) {
            bf16x8 bw[4];
#pragma unroll
            for (int ks = 0; ks < 4; ++ks)
                bw[ks] = *(const bf16x8*)((const char*)sW1[cur] + (n * 16 + lo) * 256
                                           + ((ks * 64 + hi * 16) ^ ((lo & 7) << 4)));
            float bb = b1[sub * 64 + n * 16 + lo];
#pragma unroll
            for (int t = 0; t < 2; ++t) {
                f32x4 hacc = {0.f, 0.f, 0.f, 0.f};
#pragma unroll
                for (int ks = 0; ks < 4; ++ks) hacc = MFMA16(a[t][ks], bw[ks], hacc, 0, 0, 0);
#pragma unroll
                for (int r = 0; r < 4; ++r) {
                    int hr = t * 16 + hi * 4 + r;
                    int hc = n * 16 + lo;
                    *(u16*)((char*)sH[w] + hr * 128 + ((2 * hc) ^ ((hr & 7) << 4))) =
                        f2bf(fmaxf(hacc[r] + bb, 0.f));
                }
            }
        }
        bf16x8 ah[2][2];
#pragma unroll
        for (int t = 0; t < 2; ++t)
#pragma unroll
            for (int ks = 0; ks < 2; ++ks) {
                int ar = t * 16 + lo;
                ah[t][ks] = *(const bf16x8*)((const char*)sH[w] + ar * 128
                                              + ((ks * 64 + hi * 16) ^ ((ar & 7) << 4)));
            }
#pragma unroll
        for (int n = 0; n < 8; ++n) {
            bf16x8 bw[2];
#pragma unroll
            for (int ks = 0; ks < 2; ++ks)
                bw[ks] = *(const bf16x8*)((const char*)sW2[cur] + (n * 16 + lo) * 128
                                           + ((ks * 64 + hi * 16) ^ ((lo & 7) << 4)));
#pragma unroll
            for (int t = 0; t < 2; ++t) {
                yacc[t][n] = MFMA16(ah[t][0], bw[0], yacc[t][n], 0, 0, 0);
                yacc[t][n] = MFMA16(ah[t][1], bw[1], yacc[t][n], 0, 0, 0);
            }
        }
        asm volatile("s_waitcnt vmcnt(0)" ::: "memory");
        __builtin_amdgcn_s_barrier();
    }

#pragma unroll
    for (int t = 0; t < 2; ++t)
#pragma unroll
        for (int n = 0; n < 8; ++n) {
            int col = n * 16 + lo;
            float bb = b2[col];
#pragma unroll
            for (int r = 0; r < 4; ++r) {
                size_t row = base + wrow + t * 16 + hi * 4 + r;
                float res = bf2f(*(const u16*)((const char*)Xb + row * 256
                                                + ((2 * col) ^ ((row & 7) << 4))));
                out[row * 128 + col] = yacc[t][n][r] + bb + res;
            }
        }
}

// ---------------------------------------------------------------------------
extern "C" void kernel_launch(void* const* d_in, const int* in_sizes, int n_in,
                              void* d_out, int out_size, void* d_ws, size_t ws_size,
                              hipStream_t stream) {
    const float* queries = (const float*)d_in[0];
    const float* keys    = (const float*)d_in[1];
    const int*   mask    = (const int*)d_in[2];
    const float* Wq = (const float*)d_in[3];
    const float* bq = (const float*)d_in[4];
    const float* Wk = (const float*)d_in[5];
    const float* bk = (const float*)d_in[6];
    const float* Wv = (const float*)d_in[7];
    const float* bv = (const float*)d_in[8];
    const float* W1 = (const float*)d_in[9];
    const float* b1 = (const float*)d_in[10];
    const float* W2 = (const float*)d_in[11];
    const float* b2 = (const float*)d_in[12];
    float* out = (float*)d_out;

    u16* wbase = (u16*)d_ws;
    u16* Qb = wbase + QB_OFF;   // also Xb
    u16* Kb = wbase + KB_OFF;
    u16* Vb = wbase + VB_OFF;
    float* bqs = (float*)(wbase + BQS_OFF);

    cvt_kernel<<<704, 256, 0, stream>>>(Wq, bq, Wk, Wv, W1, W2, wbase, bqs);
    proj_q_kernel<<<800, 256, 0, stream>>>(queries, wbase + WQ_OFF, bqs, Qb);
    proj_kv_kernel<<<800, 256, 0, stream>>>(keys, wbase + WK_OFF, wbase + WV_OFF,
                                            bk, bv, Kb, Vb);
    attn_kernel<<<B_ * 4, 256, 0, stream>>>(Qb, Kb, Vb, mask, queries, Qb);
    ffn_kernel<<<800, 256, 0, stream>>>(Qb, wbase + W1_OFF, wbase + W2_OFF, b1, b2, out);
}

// Round 5
// 152.633 us; speedup vs baseline: 1.1112x; 1.1112x over previous
//
#include <hip/hip_runtime.h>

#define B_  512
#define S_  200
#define M_  102400

typedef short bf16x8 __attribute__((ext_vector_type(8)));
typedef float f32x4  __attribute__((ext_vector_type(4)));
typedef unsigned short u16;
typedef u16 us4 __attribute__((ext_vector_type(4)));
typedef unsigned int u32;

#define MFMA16 __builtin_amdgcn_mfma_f32_16x16x32_bf16
#define GLDS(gp, lp) __builtin_amdgcn_global_load_lds( \
    (const __attribute__((address_space(1))) unsigned int*)(gp), \
    (__attribute__((address_space(3))) unsigned int*)(lp), 16, 0, 0)

__device__ __forceinline__ u16 f2bf(float f) {
    union { float f; unsigned u; } v; v.f = f;
    unsigned r = v.u + 0x7fffu + ((v.u >> 16) & 1u);
    return (u16)(r >> 16);
}
__device__ __forceinline__ float bf2f(u16 x) {
    union { unsigned u; float f; } v; v.u = ((unsigned)x) << 16;
    return v.f;
}
__device__ __forceinline__ int swz(int row, int b) { return b ^ ((row & 7) << 4); }

// ws layout (u16 units)
#define WQ_OFF   0
#define WK_OFF   16384
#define WV_OFF   32768
#define W1_OFF   49152
#define W2_OFF   114688
#define BQS_OFF  180224
#define QB_OFF   262144   // also Xb (aliased)
#define KB_OFF   (QB_OFF + 13107200)
#define VB_OFF   (KB_OFF + 13107200)

// ---------------------------------------------------------------------------
__global__ __launch_bounds__(256) void cvt_kernel(
    const float* __restrict__ Wq, const float* __restrict__ bq,
    const float* __restrict__ Wk, const float* __restrict__ Wv,
    const float* __restrict__ W1, const float* __restrict__ W2,
    u16* __restrict__ wdst, float* __restrict__ bqs)
{
    const float QSC = 0.17677669529663689f;
    int idx = blockIdx.x * 256 + threadIdx.x;
    if (idx < 128) bqs[idx] = bq[idx] * QSC;
    if (idx < 49152) {
        int wsel = idx >> 14, r = (idx >> 7) & 127, c = idx & 127;
        const float* src = wsel == 0 ? Wq : (wsel == 1 ? Wk : Wv);
        float v = src[idx & 16383];
        if (wsel == 0) v *= QSC;
        *(u16*)((char*)(wdst + wsel * 16384) + r * 256 + swz(r, 2 * c)) = f2bf(v);
    } else if (idx < 114688) {
        int i = idx - 49152;
        int r_g = i >> 7, c = i & 127;
        int sub = r_g >> 6, fr = r_g & 63;
        *(u16*)((char*)(wdst + W1_OFF) + sub * 16384 + fr * 256 + ((2 * c) ^ ((fr & 7) << 4)))
            = f2bf(W1[i]);
    } else if (idx < 180224) {
        int i = idx - 114688;
        int r_out = i >> 9, c_ff = i & 511;
        int sub = c_ff >> 6, lc = c_ff & 63;
        *(u16*)((char*)(wdst + W2_OFF) + sub * 16384 + r_out * 128 + ((2 * lc) ^ ((r_out & 7) << 4)))
            = f2bf(W2[i]);
    }
}

// ---------------------------------------------------------------------------
// Q projection -> swizzled bf16 Qb (pre-scaled by 1/sqrt(D))
// ---------------------------------------------------------------------------
__global__ __launch_bounds__(256) void proj_q_kernel(
    const float* __restrict__ X, const u16* __restrict__ Ws,
    const float* __restrict__ bqs, u16* __restrict__ Y)
{
    __shared__ __align__(16) u16 sW[16384];
    const int tid = threadIdx.x, w = tid >> 6, lane = tid & 63;
    const int lo = lane & 15, hi = lane >> 4;
    const int base = blockIdx.x * 128;

#pragma unroll
    for (int k = 0; k < 8; ++k) {
        int seg = w * 8 + k;
        GLDS((const char*)Ws + seg * 1024 + lane * 16, (char*)sW + seg * 1024);
    }

    bf16x8 a[2][4];
#pragma unroll
    for (int t = 0; t < 2; ++t) {
        const float* rp = X + (size_t)(base + w * 32 + t * 16 + lo) * 128;
#pragma unroll
        for (int ks = 0; ks < 4; ++ks) {
            float4 v0 = *(const float4*)(rp + ks * 32 + hi * 8);
            float4 v1 = *(const float4*)(rp + ks * 32 + hi * 8 + 4);
            union { bf16x8 v; u16 s[8]; } af;
            af.s[0]=f2bf(v0.x); af.s[1]=f2bf(v0.y); af.s[2]=f2bf(v0.z); af.s[3]=f2bf(v0.w);
            af.s[4]=f2bf(v1.x); af.s[5]=f2bf(v1.y); af.s[6]=f2bf(v1.z); af.s[7]=f2bf(v1.w);
            a[t][ks] = af.v;
        }
    }
    asm volatile("s_waitcnt vmcnt(0)" ::: "memory");
    __builtin_amdgcn_s_barrier();

#pragma unroll
    for (int n = 0; n < 8; ++n) {
        bf16x8 bf[4];
#pragma unroll
        for (int ks = 0; ks < 4; ++ks)
            bf[ks] = *(const bf16x8*)((const char*)sW + (n*16+lo)*256 + swz(lo, ks*64 + hi*16));
        float bb = bqs[n * 16 + lo];
#pragma unroll
        for (int t = 0; t < 2; ++t) {
            f32x4 acc = {0.f, 0.f, 0.f, 0.f};
#pragma unroll
            for (int ks = 0; ks < 4; ++ks) acc = MFMA16(a[t][ks], bf[ks], acc, 0, 0, 0);
#pragma unroll
            for (int r = 0; r < 4; ++r) {
                int row = base + w * 32 + t * 16 + hi * 4 + r;
                *(u16*)((char*)Y + (size_t)row * 256 + swz(row, n * 32 + 2 * lo)) =
                    f2bf(acc[r] + bb);
            }
        }
    }
}

// ---------------------------------------------------------------------------
// Fused K/V projection. Plain [M][128] bf16 outputs.
// ---------------------------------------------------------------------------
__global__ __launch_bounds__(256) void proj_kv_kernel(
    const float* __restrict__ X, const u16* __restrict__ Wks, const u16* __restrict__ Wvs,
    const float* __restrict__ bk, const float* __restrict__ bv,
    u16* __restrict__ K, u16* __restrict__ V)
{
    __shared__ __align__(16) u16 sWk[16384];
    __shared__ __align__(16) u16 sWv[16384];
    const int tid = threadIdx.x, w = tid >> 6, lane = tid & 63;
    const int lo = lane & 15, hi = lane >> 4;
    const int base = blockIdx.x * 128;

#pragma unroll
    for (int k = 0; k < 8; ++k) {
        int seg = w * 8 + k;
        GLDS((const char*)Wks + seg * 1024 + lane * 16, (char*)sWk + seg * 1024);
        GLDS((const char*)Wvs + seg * 1024 + lane * 16, (char*)sWv + seg * 1024);
    }

    bf16x8 a[2][4];
#pragma unroll
    for (int t = 0; t < 2; ++t) {
        const float* rp = X + (size_t)(base + w * 32 + t * 16 + lo) * 128;
#pragma unroll
        for (int ks = 0; ks < 4; ++ks) {
            float4 v0 = *(const float4*)(rp + ks * 32 + hi * 8);
            float4 v1 = *(const float4*)(rp + ks * 32 + hi * 8 + 4);
            union { bf16x8 v; u16 s[8]; } af;
            af.s[0]=f2bf(v0.x); af.s[1]=f2bf(v0.y); af.s[2]=f2bf(v0.z); af.s[3]=f2bf(v0.w);
            af.s[4]=f2bf(v1.x); af.s[5]=f2bf(v1.y); af.s[6]=f2bf(v1.z); af.s[7]=f2bf(v1.w);
            a[t][ks] = af.v;
        }
    }
    asm volatile("s_waitcnt vmcnt(0)" ::: "memory");
    __builtin_amdgcn_s_barrier();

#pragma unroll
    for (int n = 0; n < 8; ++n) {
        bf16x8 bf[4];
#pragma unroll
        for (int ks = 0; ks < 4; ++ks)
            bf[ks] = *(const bf16x8*)((const char*)sWk + (n*16+lo)*256 + swz(lo, ks*64 + hi*16));
        float bb = bk[n * 16 + lo];
#pragma unroll
        for (int t = 0; t < 2; ++t) {
            f32x4 acc = {0.f, 0.f, 0.f, 0.f};
#pragma unroll
            for (int ks = 0; ks < 4; ++ks) acc = MFMA16(a[t][ks], bf[ks], acc, 0, 0, 0);
#pragma unroll
            for (int r = 0; r < 4; ++r) {
                size_t row = base + w * 32 + t * 16 + hi * 4 + r;
                K[row * 128 + n * 16 + lo] = f2bf(acc[r] + bb);
            }
        }
    }
#pragma unroll
    for (int n = 0; n < 8; ++n) {
        bf16x8 bf[4];
#pragma unroll
        for (int ks = 0; ks < 4; ++ks)
            bf[ks] = *(const bf16x8*)((const char*)sWv + (n*16+lo)*256 + swz(lo, ks*64 + hi*16));
        float bb = bv[n * 16 + lo];
#pragma unroll
        for (int t = 0; t < 2; ++t) {
            f32x4 acc = {0.f, 0.f, 0.f, 0.f};
#pragma unroll
            for (int ks = 0; ks < 4; ++ks) acc = MFMA16(a[t][ks], bf[ks], acc, 0, 0, 0);
#pragma unroll
            for (int r = 0; r < 4; ++r) {
                size_t row = base + w * 32 + t * 16 + hi * 4 + r;
                V[row * 128 + n * 16 + lo] = f2bf(acc[r] + bb);
            }
        }
    }
}

// ---------------------------------------------------------------------------
// Attention: swapped QK^T, in-register P, permuted-k PV, multiplicative mask.
// LDS trimmed to 32,448 B -> 5 blocks/CU; launch_bounds caps VGPR at 102.
// k-slot map per chunk: slot j of lane-hi  <->  key = c0 + 16*(j>>2) + 4*hi + (j&3)
// ---------------------------------------------------------------------------
__global__ __launch_bounds__(256, 5) void attn_kernel(
    const u16* __restrict__ Qb, const u16* __restrict__ Kb, const u16* __restrict__ Vb,
    const int* __restrict__ mask, const float* __restrict__ queries, u16* __restrict__ Xb)
{
    __shared__ __align__(16) u16 sK[208][40];    // key pos x d (rows 200..207 zero)
    __shared__ __align__(16) u16 sVt[32][240];   // d x permuted key pos
    __shared__ __align__(16) u16 sMk[224];       // permuted mask: bf16 1.0 or 0

    const int tid = threadIdx.x;
    const int b   = blockIdx.x >> 2;
    const int h   = blockIdx.x & 3;
    const size_t rowbase = (size_t)b * 200;

    // K: 16B vector loads
    for (int slot = tid; slot < 800; slot += 256) {
        int s = slot >> 2, part = slot & 3;
        *(bf16x8*)&sK[s][part * 8] =
            *(const bf16x8*)(Kb + (rowbase + s) * 128 + h * 32 + part * 8);
    }
    if (tid < 32) {   // zero rows 200..207
        int s = 200 + (tid >> 2), part = tid & 3;
        bf16x8 z = {0,0,0,0,0,0,0,0};
        *(bf16x8*)&sK[s][part * 8] = z;
    }
    // V^T, permuted key positions (4-aligned groups contiguous)
    for (int slot = tid; slot < 1792; slot += 256) {
        int d = slot & 31, sg = slot >> 5;
        int s0 = sg * 4;
        int c0 = s0 & ~31, a = (s0 & 31) >> 2;
        int pos = c0 + (a & 3) * 8 + (a >> 2) * 4;
        us4 v;
#pragma unroll
        for (int j = 0; j < 4; ++j) {
            int s = s0 + j;
            v[j] = (s < 200) ? Vb[(rowbase + s) * 128 + h * 32 + d] : (u16)0;
        }
        *(us4*)&sVt[d][pos] = v;
    }
    // permuted multiplicative mask
    for (int i = tid; i < 224; i += 256) {
        int c0 = i & ~31, local = i & 31;
        int hh = local >> 3, j = local & 7;
        int key = c0 + 16 * (j >> 2) + 4 * hh + (j & 3);
        sMk[i] = (key < 200 && mask[rowbase + key] != 0) ? (u16)0x3F80 : (u16)0;
    }
    __syncthreads();

    const int w = tid >> 6, lane = tid & 63;
    const int lo = lane & 15, hi = lane >> 4;

    for (int qb = w; qb < 13; qb += 4) {
        int qrow = qb * 16 + lo;
        if (qrow > 199) qrow = 199;
        bf16x8 qf = *(const bf16x8*)((const char*)Qb + (size_t)(rowbase + qrow) * 256
                                      + swz(qrow, h * 64 + hi * 16));

        f32x4 acc0 = {0.f, 0.f, 0.f, 0.f}, acc1 = {0.f, 0.f, 0.f, 0.f};
        float psum = 0.f;

#pragma unroll 1
        for (int kt = 0; kt < 7; ++kt) {
            int c0 = kt * 32;
            bf16x8 k0 = *(const bf16x8*)&sK[c0 + lo][hi * 8];
            int r1 = c0 + 16 + lo; r1 = (r1 > 207) ? 207 : r1;   // kt=6 upper half is masked
            bf16x8 k1 = *(const bf16x8*)&sK[r1][hi * 8];
            f32x4 z = {0.f, 0.f, 0.f, 0.f};
            f32x4 s0 = MFMA16(k0, qf, z, 0, 0, 0);   // S^T[key=c0+4hi+r][q=lo]
            f32x4 s1 = MFMA16(k1, qf, z, 0, 0, 0);
            us4 mk0 = *(const us4*)&sMk[c0 + hi * 8];
            us4 mk1 = *(const us4*)&sMk[c0 + hi * 8 + 4];
            union { bf16x8 v; u32 d[4]; } pa;
            {
                float p0 = __expf(s0[0]) * __uint_as_float((u32)mk0[0] << 16);
                float p1 = __expf(s0[1]) * __uint_as_float((u32)mk0[1] << 16);
                float p2 = __expf(s0[2]) * __uint_as_float((u32)mk0[2] << 16);
                float p3 = __expf(s0[3]) * __uint_as_float((u32)mk0[3] << 16);
                psum += (p0 + p1) + (p2 + p3);
                pa.d[0] = (__float_as_uint(p0) >> 16) | (__float_as_uint(p1) & 0xffff0000u);
                pa.d[1] = (__float_as_uint(p2) >> 16) | (__float_as_uint(p3) & 0xffff0000u);
            }
            {
                float p0 = __expf(s1[0]) * __uint_as_float((u32)mk1[0] << 16);
                float p1 = __expf(s1[1]) * __uint_as_float((u32)mk1[1] << 16);
                float p2 = __expf(s1[2]) * __uint_as_float((u32)mk1[2] << 16);
                float p3 = __expf(s1[3]) * __uint_as_float((u32)mk1[3] << 16);
                psum += (p0 + p1) + (p2 + p3);
                pa.d[2] = (__float_as_uint(p0) >> 16) | (__float_as_uint(p1) & 0xffff0000u);
                pa.d[3] = (__float_as_uint(p2) >> 16) | (__float_as_uint(p3) & 0xffff0000u);
            }
            bf16x8 v0 = *(const bf16x8*)&sVt[lo][c0 + hi * 8];
            bf16x8 v1 = *(const bf16x8*)&sVt[16 + lo][c0 + hi * 8];
            acc0 = MFMA16(pa.v, v0, acc0, 0, 0, 0);
            acc1 = MFMA16(pa.v, v1, acc1, 0, 0, 0);
        }
        // psum holds partials for q=lo over this lane's keys; reduce across hi
        psum += __shfl_xor(psum, 16);
        psum += __shfl_xor(psum, 32);
        float inv = 1.f / psum;
        float invr[4];
#pragma unroll
        for (int r = 0; r < 4; ++r)
            invr[r] = __shfl(inv, 4 * hi + r, 16);
#pragma unroll
        for (int r = 0; r < 4; ++r) {
            int row = qb * 16 + hi * 4 + r;
            if (row < 200) {
                size_t o  = (rowbase + row) * 128 + h * 32;
                size_t rb = (rowbase + row) * 256;
                *(u16*)((char*)Xb + rb + swz(row, h * 64 + 2 * lo)) =
                    f2bf(acc0[r] * invr[r] + queries[o + lo]);
                *(u16*)((char*)Xb + rb + swz(row, h * 64 + 32 + 2 * lo)) =
                    f2bf(acc1[r] * invr[r] + queries[o + 16 + lo]);
            }
        }
    }
}

// ---------------------------------------------------------------------------
// Fused FFN: out = relu(X@W1^T+b1)@W2^T + b2 + X.  X = swizzled bf16 Xb.
// ---------------------------------------------------------------------------
__global__ __launch_bounds__(256) void ffn_kernel(
    const u16* __restrict__ Xb, const u16* __restrict__ W1s, const u16* __restrict__ W2s,
    const float* __restrict__ b1, const float* __restrict__ b2, float* __restrict__ out)
{
    __shared__ __align__(16) u16 sW1[2][8192];
    __shared__ __align__(16) u16 sW2[2][8192];
    __shared__ __align__(16) u16 sH[4][2048];
    const int tid = threadIdx.x, w = tid >> 6, lane = tid & 63;
    const int lo = lane & 15, hi = lane >> 4;
    const size_t base = (size_t)blockIdx.x * 128;
    const int wrow = w * 32;

#pragma unroll
    for (int k = 0; k < 4; ++k) {
        int seg = w * 4 + k;
        GLDS((const char*)W1s + seg * 1024 + lane * 16, (char*)sW1[0] + seg * 1024);
        GLDS((const char*)W2s + seg * 1024 + lane * 16, (char*)sW2[0] + seg * 1024);
    }

    bf16x8 a[2][4];
#pragma unroll
    for (int t = 0; t < 2; ++t) {
        size_t row = base + wrow + t * 16 + lo;
#pragma unroll
        for (int ks = 0; ks < 4; ++ks)
            a[t][ks] = *(const bf16x8*)((const char*)Xb + row * 256
                                         + ((ks * 64 + hi * 16) ^ ((lo & 7) << 4)));
    }

    f32x4 yacc[2][8];
#pragma unroll
    for (int t = 0; t < 2; ++t)
#pragma unroll
        for (int n = 0; n < 8; ++n) yacc[t][n] = (f32x4){0.f, 0.f, 0.f, 0.f};

    asm volatile("s_waitcnt vmcnt(0)" ::: "memory");
    __builtin_amdgcn_s_barrier();

    for (int sub = 0; sub < 8; ++sub) {
        int cur = sub & 1, nxt = cur ^ 1;
        if (sub < 7) {
#pragma unroll
            for (int k = 0; k < 4; ++k) {
                int seg = w * 4 + k;
                GLDS((const char*)W1s + (sub + 1) * 16384 + seg * 1024 + lane * 16,
                     (char*)sW1[nxt] + seg * 1024);
                GLDS((const char*)W2s + (sub + 1) * 16384 + seg * 1024 + lane * 16,
                     (char*)sW2[nxt] + seg * 1024);
            }
        }
#pragma unroll
        for (int n = 0; n < 4; ++n) {
            bf16x8 bw[4];
#pragma unroll
            for (int ks = 0; ks < 4; ++ks)
                bw[ks] = *(const bf16x8*)((const char*)sW1[cur] + (n * 16 + lo) * 256
                                           + ((ks * 64 + hi * 16) ^ ((lo & 7) << 4)));
            float bb = b1[sub * 64 + n * 16 + lo];
#pragma unroll
            for (int t = 0; t < 2; ++t) {
                f32x4 hacc = {0.f, 0.f, 0.f, 0.f};
#pragma unroll
                for (int ks = 0; ks < 4; ++ks) hacc = MFMA16(a[t][ks], bw[ks], hacc, 0, 0, 0);
#pragma unroll
                for (int r = 0; r < 4; ++r) {
                    int hr = t * 16 + hi * 4 + r;
                    int hc = n * 16 + lo;
                    *(u16*)((char*)sH[w] + hr * 128 + ((2 * hc) ^ ((hr & 7) << 4))) =
                        f2bf(fmaxf(hacc[r] + bb, 0.f));
                }
            }
        }
        bf16x8 ah[2][2];
#pragma unroll
        for (int t = 0; t < 2; ++t)
#pragma unroll
            for (int ks = 0; ks < 2; ++ks) {
                int ar = t * 16 + lo;
                ah[t][ks] = *(const bf16x8*)((const char*)sH[w] + ar * 128
                                              + ((ks * 64 + hi * 16) ^ ((ar & 7) << 4)));
            }
#pragma unroll
        for (int n = 0; n < 8; ++n) {
            bf16x8 bw[2];
#pragma unroll
            for (int ks = 0; ks < 2; ++ks)
                bw[ks] = *(const bf16x8*)((const char*)sW2[cur] + (n * 16 + lo) * 128
                                           + ((ks * 64 + hi * 16) ^ ((lo & 7) << 4)));
#pragma unroll
            for (int t = 0; t < 2; ++t) {
                yacc[t][n] = MFMA16(ah[t][0], bw[0], yacc[t][n], 0, 0, 0);
                yacc[t][n] = MFMA16(ah[t][1], bw[1], yacc[t][n], 0, 0, 0);
            }
        }
        asm volatile("s_waitcnt vmcnt(0)" ::: "memory");
        __builtin_amdgcn_s_barrier();
    }

#pragma unroll
    for (int t = 0; t < 2; ++t)
#pragma unroll
        for (int n = 0; n < 8; ++n) {
            int col = n * 16 + lo;
            float bb = b2[col];
#pragma unroll
            for (int r = 0; r < 4; ++r) {
                size_t row = base + wrow + t * 16 + hi * 4 + r;
                float res = bf2f(*(const u16*)((const char*)Xb + row * 256
                                                + ((2 * col) ^ ((row & 7) << 4))));
                out[row * 128 + col] = yacc[t][n][r] + bb + res;
            }
        }
}

// ---------------------------------------------------------------------------
extern "C" void kernel_launch(void* const* d_in, const int* in_sizes, int n_in,
                              void* d_out, int out_size, void* d_ws, size_t ws_size,
                              hipStream_t stream) {
    const float* queries = (const float*)d_in[0];
    const float* keys    = (const float*)d_in[1];
    const int*   mask    = (const int*)d_in[2];
    const float* Wq = (const float*)d_in[3];
    const float* bq = (const float*)d_in[4];
    const float* Wk = (const float*)d_in[5];
    const float* bk = (const float*)d_in[6];
    const float* Wv = (const float*)d_in[7];
    const float* bv = (const float*)d_in[8];
    const float* W1 = (const float*)d_in[9];
    const float* b1 = (const float*)d_in[10];
    const float* W2 = (const float*)d_in[11];
    const float* b2 = (const float*)d_in[12];
    float* out = (float*)d_out;

    u16* wbase = (u16*)d_ws;
    u16* Qb = wbase + QB_OFF;   // also Xb
    u16* Kb = wbase + KB_OFF;
    u16* Vb = wbase + VB_OFF;
    float* bqs = (float*)(wbase + BQS_OFF);

    cvt_kernel<<<704, 256, 0, stream>>>(Wq, bq, Wk, Wv, W1, W2, wbase, bqs);
    proj_q_kernel<<<800, 256, 0, stream>>>(queries, wbase + WQ_OFF, bqs, Qb);
    proj_kv_kernel<<<800, 256, 0, stream>>>(keys, wbase + WK_OFF, wbase + WV_OFF,
                                            bk, bv, Kb, Vb);
    attn_kernel<<<B_ * 4, 256, 0, stream>>>(Qb, Kb, Vb, mask, queries, Qb);
    ffn_kernel<<<800, 256, 0, stream>>>(Qb, wbase + W1_OFF, wbase + W2_OFF, b1, b2, out);
}